// Round 1
// 345.023 us; speedup vs baseline: 1.1472x; 1.1472x over previous
//
#include <hip/hip_runtime.h>
#include <math.h>

#define ROW_N 512
#define N_ITERS 100
#define LAMBDA 10.0f

typedef float f2 __attribute__((ext_vector_type(2)));

__device__ __forceinline__ f2 splat(float s) { f2 r; r.x = s; r.y = s; return r; }
__device__ __forceinline__ f2 ffma(f2 a, f2 b, f2 c) {
    return __builtin_elementwise_fma(a, b, c);
}

// Precompute FISTA momentum coefficients coef[k] = (t_k - 1) / t_{k+1}.
__global__ void coef_kernel(float* __restrict__ coefs) {
    if (threadIdx.x == 0) {
        float t = 1.0f;
        for (int k = 0; k < N_ITERS; ++k) {
            float t_new = 0.5f * (1.0f + sqrtf(1.0f + 4.0f * t * t));
            coefs[k] = (t - 1.0f) / t_new;
            t = t_new;
        }
    }
}

// TWO rows per wave packed in float2 components; 8 elems/lane; one row-pair
// per wave (8192 waves, 2048 blocks). This revision replaces the dd-route
// (D z then D^T d: ~6.5 ops/elem) with the DIRECT pentadiagonal stencil
// (5 ops/elem):  u = ay + (C-6B) z_i + 4B (z_{i-1}+z_{i+1}) - B (z_{i-2}+z_{i+2})
// Boundary rows are made EXACT by ghost values (verified against rows
// 0,1,n-2,n-1 of D^T D):  z_{-1}=2z0-z1, z_{-2}=3z0-2z1 (mirrored at bottom).
// Jacobi semantics under in-place z update kept via SSA renames of old z
// (zero-cost); explicit xA/xB ping-pong deletes the per-iter x copies;
// momentum uses scalar fmaf with the SGPR coef (no splat movs).
// Update order 2..7,0,1 preserves shuffle latency slack: down-shuffles are
// consumed ~40 insts later (next step, before elem 6), up-shuffles ~20 insts
// later (end-of-step select).
template <bool USE_TABLE>
__global__ __launch_bounds__(256)
__attribute__((amdgpu_waves_per_eu(2, 8)))
void fista_kernel(
    const float* __restrict__ in, float* __restrict__ out,
    const float* __restrict__ coefs, int n_rows)
{
    const int pid  = (int)((blockIdx.x * 256u + threadIdx.x) >> 6); // row pair
    const int lane = (int)(threadIdx.x & 63u);
    const int n_pairs = (n_rows + 1) >> 1;
    if (pid >= n_pairs) return;

    const bool lane_lo = (lane == 0);
    const bool lane_hi = (lane == 63);

    const int r0 = pid * 2;
    const int r1 = (r0 + 1 < n_rows) ? r0 + 1 : r0;
    const float* rowA = in + (size_t)r0 * ROW_N + lane * 8;
    const float* rowB = in + (size_t)r1 * ROW_N + lane * 8;

    const float A = 1.0f / (1.0f + 16.0f * LAMBDA);   // 2*step
    const float B = LAMBDA / (1.0f + 16.0f * LAMBDA); // 2*step*lam
    const float C = 1.0f - A;
    const f2 K0 = splat(C - 6.0f * B);  // center coeff
    const f2 B4 = splat(4.0f * B);      // +-1 neighbor coeff
    const f2 Bn = splat(-B);            // +-2 neighbor coeff
    const f2 Av = splat(A);
    const f2 TWO = splat(2.0f);

    f2 y[8], ay[8], xA[8], xB[8], z[8];
    {
        const float4 a0 = *(const float4*)(rowA);
        const float4 a1 = *(const float4*)(rowA + 4);
        const float4 b0 = *(const float4*)(rowB);
        const float4 b1 = *(const float4*)(rowB + 4);
        y[0].x = a0.x; y[1].x = a0.y; y[2].x = a0.z; y[3].x = a0.w;
        y[4].x = a1.x; y[5].x = a1.y; y[6].x = a1.z; y[7].x = a1.w;
        y[0].y = b0.x; y[1].y = b0.y; y[2].y = b0.z; y[3].y = b0.w;
        y[4].y = b1.x; y[5].y = b1.y; y[6].y = b1.z; y[7].y = b1.w;
    }

    // loop-carried halos: zm1/zm2 = old z7/z6 of lane-1 (ghost-selected);
    // sp0/sp1 = RAW shuffled old z0/z1 of lane+1 (ghost-selected inside step)
    f2 zm1, zm2, sp0, sp1;

    // one element update; t1 = a+b = z_{i-1}+z_{i+1} (old vintage),
    // t2 = c+d = z_{i-2}+z_{i+2} (old vintage)
    auto upd = [&](int i, f2 a, f2 b, f2 c, f2 d,
                   const f2* xin, f2* xout, float cf) {
        f2 t1 = a + b;
        f2 t2 = c + d;
        f2 u = ffma(K0, z[i], ay[i]);
        u = ffma(B4, t1, u);
        u = ffma(Bn, t2, u);
        f2 xe;
        xe.x = __builtin_amdgcn_fmed3f(u.x, 0.0f, y[i].x); // clip(u,0,y)
        xe.y = __builtin_amdgcn_fmed3f(u.y, 0.0f, y[i].y);
        f2 dd = xe - xin[i];
        f2 zn;
        zn.x = fmaf(cf, dd.x, xe.x);   // scalar fma: coef stays in SGPR
        zn.y = fmaf(cf, dd.y, xe.y);
        z[i] = zn;
        xout[i] = xe;
    };

    auto step = [&](const f2* xin, f2* xout, float cf) {
        // captures of old z needed after in-place writes (SSA renames, free)
        const f2 z2o = z[2], z3o = z[3], z4o = z[4], z5o = z[5];
        upd(2, z[1], z[3], z[0], z[4], xin, xout, cf);
        upd(3, z2o,  z[4], z[1], z[5], xin, xout, cf);
        upd(4, z3o,  z[5], z2o,  z[6], xin, xout, cf);
        upd(5, z4o,  z[6], z3o,  z[7], xin, xout, cf);

        // down-halo for THIS step (old vintage): ghosts from old z6,z7;
        // sp0/sp1 raw shuffles issued at END of previous step (~40 insts ago)
        f2 gp0 = ffma(TWO, z[7], -z[6]);   // 2*z7 - z6
        f2 gp1 = ffma(TWO, gp0, -z[7]);    // 3*z7 - 2*z6
        f2 zp0, zp1;
        zp0.x = lane_hi ? gp0.x : sp0.x;  zp0.y = lane_hi ? gp0.y : sp0.y;
        zp1.x = lane_hi ? gp1.x : sp1.x;  zp1.y = lane_hi ? gp1.y : sp1.y;

        const f2 z6o = z[6];
        upd(6, z5o, z[7], z4o, zp0, xin, xout, cf);
        upd(7, z6o, zp0,  z5o, zp1, xin, xout, cf);

        // up-shuffles from NEW z6,z7; consumed at end-of-step select (~20 insts)
        f2 um1, um2;
        um2.x = __shfl_up(z[6].x, 1); um2.y = __shfl_up(z[6].y, 1);
        um1.x = __shfl_up(z[7].x, 1); um1.y = __shfl_up(z[7].y, 1);

        const f2 z0o = z[0];
        upd(0, zm1, z[1], zm2, z2o, xin, xout, cf);
        upd(1, z0o, z2o,  zm1, z3o, xin, xout, cf);

        // zm for NEXT step: ghosts from NEW z0,z1
        f2 gm1 = ffma(TWO, z[0], -z[1]);
        f2 gm2 = ffma(TWO, gm1, -z[0]);
        zm1.x = lane_lo ? gm1.x : um1.x;  zm1.y = lane_lo ? gm1.y : um1.y;
        zm2.x = lane_lo ? gm2.x : um2.x;  zm2.y = lane_lo ? gm2.y : um2.y;

        // down-shuffles from NEW z0,z1 (selected in NEXT step before elem 6)
        sp0.x = __shfl_down(z[0].x, 1); sp0.y = __shfl_down(z[0].y, 1);
        sp1.x = __shfl_down(z[1].x, 1); sp1.y = __shfl_down(z[1].y, 1);
    };

    #pragma unroll 1
    for (int pass = 0; pass < 2; ++pass) {
        #pragma unroll
        for (int i = 0; i < 8; ++i) {
            ay[i] = Av * y[i];
            xA[i] = y[i];   // x0 = proj(y) = y  (y >= 0 by construction)
            z[i]  = y[i];
        }
        // prime halos (vintage: initial z)
        {
            f2 um1, um2;
            um2.x = __shfl_up(z[6].x, 1); um2.y = __shfl_up(z[6].y, 1);
            um1.x = __shfl_up(z[7].x, 1); um1.y = __shfl_up(z[7].y, 1);
            f2 gm1 = ffma(TWO, z[0], -z[1]);
            f2 gm2 = ffma(TWO, gm1, -z[0]);
            zm1.x = lane_lo ? gm1.x : um1.x;  zm1.y = lane_lo ? gm1.y : um1.y;
            zm2.x = lane_lo ? gm2.x : um2.x;  zm2.y = lane_lo ? gm2.y : um2.y;
            sp0.x = __shfl_down(z[0].x, 1); sp0.y = __shfl_down(z[0].y, 1);
            sp1.x = __shfl_down(z[1].x, 1); sp1.y = __shfl_down(z[1].y, 1);
        }

        float tcur = 1.0f;
        #pragma unroll 1
        for (int it = 0; it < N_ITERS; it += 2) {
            float c0, c1;
            if (USE_TABLE) {
                c0 = coefs[it];
                c1 = coefs[it + 1];
            } else {
                float tn  = 0.5f * (1.0f + sqrtf(fmaf(4.0f * tcur, tcur, 1.0f)));
                c0 = (tcur - 1.0f) / tn;
                float tn2 = 0.5f * (1.0f + sqrtf(fmaf(4.0f * tn, tn, 1.0f)));
                c1 = (tn - 1.0f) / tn2;
                tcur = tn2;
            }
            step(xA, xB, c0);   // reads xA as x_old, writes xB
            step(xB, xA, c1);   // N_ITERS even -> final x lands in xA
        }

        if (pass == 0) {
            #pragma unroll
            for (int i = 0; i < 8; ++i) y[i] = xA[i];  // pass 2: y = pass-1 x
        }
    }

    float* orowA = out + (size_t)r0 * ROW_N + lane * 8;
    *(float4*)(orowA)     = make_float4(xA[0].x, xA[1].x, xA[2].x, xA[3].x);
    *(float4*)(orowA + 4) = make_float4(xA[4].x, xA[5].x, xA[6].x, xA[7].x);
    if (r1 > r0) {
        float* orowB = out + (size_t)r1 * ROW_N + lane * 8;
        *(float4*)(orowB)     = make_float4(xA[0].y, xA[1].y, xA[2].y, xA[3].y);
        *(float4*)(orowB + 4) = make_float4(xA[4].y, xA[5].y, xA[6].y, xA[7].y);
    }
}

extern "C" void kernel_launch(void* const* d_in, const int* in_sizes, int n_in,
                              void* d_out, int out_size, void* d_ws, size_t ws_size,
                              hipStream_t stream) {
    const float* in = (const float*)d_in[0];
    float* out = (float*)d_out;

    const int total   = in_sizes[0];
    const int n_rows  = total / ROW_N;          // 16384
    const int n_pairs = (n_rows + 1) >> 1;      // 8192 waves, 1 pair/wave
    const int waves_per_block = 4;              // 256 threads
    const int blocks = (n_pairs + waves_per_block - 1) / waves_per_block;

    if (ws_size >= N_ITERS * sizeof(float)) {
        float* coefs = (float*)d_ws;
        coef_kernel<<<1, 64, 0, stream>>>(coefs);
        fista_kernel<true><<<blocks, 256, 0, stream>>>(in, out, coefs, n_rows);
    } else {
        fista_kernel<false><<<blocks, 256, 0, stream>>>(in, out, nullptr, n_rows);
    }
}